// Round 8
// baseline (73.229 us; speedup 1.0000x reference)
//
#include <hip/hip_runtime.h>

#define NPROTO 512
#define NBLK 8
#define DB 128
#define DM 1024
#define TMR 128         // query rows per block (4 waves x 32 rows)
#define PCH 64          // protos per chunk (8 chunks)

#define IDX_OFF  8388608
#define VQ_OFF   8454144
#define CL_OFF   8454145

typedef unsigned short u16;
typedef __attribute__((ext_vector_type(8))) _Float16 f16x8;
typedef __attribute__((ext_vector_type(4))) float f32x4;

// ---- ws layout (bytes) ----
#define BH_B   0u
#define BL_B   1048576u
#define CN_B   2097152u
#define PART_B 2113536u
#define WS_NEED (PART_B + 4096u)

__device__ __forceinline__ void gl_lds16(const u16* g, u16* l) {
    __builtin_amdgcn_global_load_lds(
        (const __attribute__((address_space(1))) unsigned int*)g,
        (__attribute__((address_space(3))) unsigned int*)l, 16, 0, 0);
}

// ---- prep: split codes into 2 f16 planes + per-proto sq-norms ----
__global__ __launch_bounds__(256) void vq_prep(const float* __restrict__ src,
                                               u16* __restrict__ hi,
                                               u16* __restrict__ lo,
                                               float* __restrict__ cn) {
    const int t  = threadIdx.x;
    const int p  = blockIdx.x * 32 + (t >> 3);
    const int e0 = (t & 7) * 16;
    const float* s = src + (size_t)p * DB + e0;
    float sq = 0.f;
    #pragma unroll
    for (int j = 0; j < 4; ++j) {
        float4 v = *(const float4*)(s + j * 4);
        ushort4 h, l;
        float x; _Float16 hf;
        #define S1(c, f) x = v.c; hf = (_Float16)x; h.f = __builtin_bit_cast(u16, hf); \
            hf = (_Float16)(x - (float)hf); l.f = __builtin_bit_cast(u16, hf); sq += x * x;
        S1(x, x) S1(y, y) S1(z, z) S1(w, w)
        #undef S1
        size_t o4 = ((size_t)p * DB + e0) / 4 + j;
        ((ushort4*)hi)[o4] = h;
        ((ushort4*)lo)[o4] = l;
    }
    sq += __shfl_xor(sq, 1, 64);
    sq += __shfl_xor(sq, 2, 64);
    sq += __shfl_xor(sq, 4, 64);
    if ((t & 7) == 0) cn[p] = sq;
}

// ================= fused MFMA main kernel =================
// r7 post-mortem: latency-bound (all pipes <40%): 1 dep-chain per B-read,
// LDS traffic 1 GB. Fix: ai=2 (32 rows/wave) + chunk=64 -> MFMA:ds_read 3:1,
// LDS traffic halved, 2 independent acc chains per B-read.
// Block 256 thr (4 waves): (256,2) = 2 blocks/CU -> 256-reg budget, no spill
// (need ~100 VGPR + 32 AGPR). qn dropped from hot path (argmin-invariant).
__global__ __launch_bounds__(256, 2) void vq_fused(
        const float* __restrict__ q, const float* __restrict__ mem,
        const u16* __restrict__ bh, const u16* __restrict__ bl,
        const float* __restrict__ cn, float* __restrict__ out,
        float* __restrict__ partials) {
    __shared__ u16 Bt[2][2][PCH][64];  // [dbuf][plane][proto][d-half] = 32 KB
    __shared__ float qn_lds[TMR];
    __shared__ int   bp[TMR];
    __shared__ float red[16];

    const int t    = threadIdx.x;
    const int lane = t & 63;
    const int w    = t >> 6;          // 0..3
    const int lrow = lane & 15;
    const int lk   = lane >> 4;       // 0..3
    const int m    = blockIdx.y;
    const int bn0  = blockIdx.x * TMR;

    // ---- staging geometry (r7-verbatim structure; 64-proto chunks) ----
    // wave w stages plane (w&1), proto rows (w>>1)*32 .. +31 (4 rounds of 8)
    const u16* plbase = (w & 1) ? bl : bh;
    const int  p_l    = (w >> 1) * 32 + (lane >> 3);
    const int  sl     = lane & 7;
    const u16* g0 = plbase + ((size_t)(m * NPROTO + p_l)) * DB
                           + ((sl ^ (p_l & 7)) * 8);    // inverse-swizzled source

#define STAGE(st_, nb_) do { \
    const u16* gs_ = g0 + ((st_) >> 1) * (PCH * DB) + ((st_) & 1) * 64; \
    u16* lb_ = &Bt[(nb_)][w & 1][(w >> 1) * 32][0]; \
    gl_lds16(gs_,           lb_); \
    gl_lds16(gs_ + 8 * DB,  lb_ + 8 * 64); \
    gl_lds16(gs_ + 16 * DB, lb_ + 16 * 64); \
    gl_lds16(gs_ + 24 * DB, lb_ + 24 * 64); \
} while (0)

    STAGE(0, 0);   // prefetch first B tile; overlaps A load/convert below

    // ---- A: 2 q-rows per lane, f32 -> 2 f16 planes in registers ----
    f16x8 ah[2][4], al[2][4];
    #pragma unroll
    for (int ai = 0; ai < 2; ++ai) {
        float qnp = 0.f;
        #pragma unroll
        for (int kst = 0; kst < 4; ++kst) {
            const float* src = q + (size_t)(bn0 + w * 32 + ai * 16 + lrow) * DM
                                 + m * DB + kst * 32 + lk * 8;
            float4 v0 = *(const float4*)src;
            float4 v1 = *(const float4*)(src + 4);
            f16x8 hv, lv;
            float x; _Float16 hh;
            #define SA(e, val) x = (val); hh = (_Float16)x; hv[e] = hh; \
                lv[e] = (_Float16)(x - (float)hh); qnp += x * x;
            SA(0, v0.x) SA(1, v0.y) SA(2, v0.z) SA(3, v0.w)
            SA(4, v1.x) SA(5, v1.y) SA(6, v1.z) SA(7, v1.w)
            #undef SA
            ah[ai][kst] = hv; al[ai][kst] = lv;
        }
        qnp += __shfl_xor(qnp, 16, 64);
        qnp += __shfl_xor(qnp, 32, 64);
        if (lk == 0) qn_lds[w * 32 + ai * 16 + lrow] = qnp;
    }

    float bestv[2][4]; int besti[2][4];
    #pragma unroll
    for (int ai = 0; ai < 2; ++ai)
        #pragma unroll
        for (int r = 0; r < 4; ++r) { bestv[ai][r] = 3.4e38f; besti[ai][r] = 0; }

    f32x4 acc[2][4];
    #pragma unroll
    for (int ai = 0; ai < 2; ++ai)
        #pragma unroll
        for (int fj = 0; fj < 4; ++fj) acc[ai][fj] = (f32x4){0.f, 0.f, 0.f, 0.f};

    const float* cnbase = cn + m * NPROTO + lrow;

    __syncthreads();   // buf0 staged + qn_lds visible

    #pragma unroll
    for (int st = 0; st < 16; ++st) {
        const int s = st & 1, buf = st & 1, ch = st >> 1;
        if (st < 15) STAGE(st + 1, buf ^ 1);
        #pragma unroll
        for (int kk = 0; kk < 2; ++kk) {
            const int kst = s * 2 + kk;
            #pragma unroll
            for (int fj = 0; fj < 4; ++fj) {
                const int rowb = fj * 16 + lrow;
                const int so   = (((kk * 4 + lk) ^ (rowb & 7)) * 8);
                f16x8 Bh = *(const f16x8*)&Bt[buf][0][rowb][so];
                f16x8 Bl = *(const f16x8*)&Bt[buf][1][rowb][so];
                #pragma unroll
                for (int ai = 0; ai < 2; ++ai) {
                    f32x4 a = acc[ai][fj];
                    a = __builtin_amdgcn_mfma_f32_16x16x32_f16(ah[ai][kst], Bh, a, 0, 0, 0);
                    a = __builtin_amdgcn_mfma_f32_16x16x32_f16(al[ai][kst], Bh, a, 0, 0, 0);
                    a = __builtin_amdgcn_mfma_f32_16x16x32_f16(ah[ai][kst], Bl, a, 0, 0, 0);
                    acc[ai][fj] = a;
                }
            }
        }
        if (s == 1) {
            // fold chunk into running argmin; dist' = cn - 2*dot (qn-free,
            // argmin-invariant; qn added back at publish for the loss)
            #pragma unroll
            for (int fj = 0; fj < 4; ++fj) {
                const int   ploc = ch * PCH + fj * 16 + lrow;
                const float cnv  = cnbase[ch * PCH + fj * 16];
                #pragma unroll
                for (int ai = 0; ai < 2; ++ai) {
                    #pragma unroll
                    for (int r = 0; r < 4; ++r) {
                        float d = cnv - 2.0f * acc[ai][fj][r];
                        if (d < bestv[ai][r]) { bestv[ai][r] = d; besti[ai][r] = ploc; }
                    }
                    acc[ai][fj] = (f32x4){0.f, 0.f, 0.f, 0.f};
                }
            }
        }
        __syncthreads();
    }

    // ---- butterfly argmin over the 16 proto-lanes ----
    #pragma unroll
    for (int ai = 0; ai < 2; ++ai)
        #pragma unroll
        for (int r = 0; r < 4; ++r) {
            float v = bestv[ai][r]; int ix = besti[ai][r];
            #pragma unroll
            for (int off = 1; off < 16; off <<= 1) {
                float v2 = __shfl_xor(v, off, 64);
                int  ix2 = __shfl_xor(ix, off, 64);
                if (v2 < v || (v2 == v && ix2 < ix)) { v = v2; ix = ix2; }
            }
            bestv[ai][r] = v; besti[ai][r] = ix;
        }

    // ---- lanes lrow==0 publish results for their 8 rows ----
    if (lrow == 0) {
        float lp = 0.f;
        #pragma unroll
        for (int ai = 0; ai < 2; ++ai)
            #pragma unroll
            for (int r = 0; r < 4; ++r) {
                int row = w * 32 + ai * 16 + lk * 4 + r;
                bp[row] = besti[ai][r];
                out[(size_t)IDX_OFF + (size_t)(bn0 + row) * NBLK + m] =
                    (float)(m * NPROTO + besti[ai][r]);
                lp += bestv[ai][r] + qn_lds[row];   // true distance for the loss
            }
        red[w * 4 + lk] = lp;
    }
    __syncthreads();

    // ---- gather winning code rows (exact f32 copy) ----
    {
        int row = t >> 1, hf = t & 1;
        int bpi = bp[row];
        const float* cv = mem + ((size_t)(m * NPROTO + bpi)) * DB + hf * 64;
        float* ov = out + (size_t)(bn0 + row) * DM + m * DB + hf * 64;
        #pragma unroll
        for (int j = 0; j < 16; ++j)
            *(float4*)(ov + j * 4) = *(const float4*)(cv + j * 4);
    }
    if (t == 0) {
        float s = 0.f;
        #pragma unroll
        for (int i = 0; i < 16; ++i) s += red[i];
        partials[blockIdx.y * gridDim.x + blockIdx.x] = s;
    }
#undef STAGE
}

// ================= fallback f32 path (used only if ws too small) =============
__global__ __launch_bounds__(256) void vq_init(const float* __restrict__ mem,
                                               float* __restrict__ cn) {
    int p = blockIdx.x * 256 + threadIdx.x;
    const float* c = mem + (size_t)p * DB;
    float s = 0.f;
    #pragma unroll 8
    for (int k = 0; k < DB; k += 4) {
        float4 v = *(const float4*)(c + k);
        s += v.x * v.x + v.y * v.y + v.z * v.z + v.w * v.w;
    }
    cn[p] = s;
}

__global__ __launch_bounds__(256, 1) void vq_main_f32(const float* __restrict__ q,
                                                      const float* __restrict__ mem,
                                                      const float* __restrict__ cn,
                                                      float* __restrict__ out,
                                                      float* __restrict__ partials) {
    __shared__ float q_lds[128 * 132];
    __shared__ float c_lds[128 * 132];
    __shared__ float red[256];

    const int t    = threadIdx.x;
    const int tile = blockIdx.x;
    const int m    = blockIdx.y;
    const int tr   = t >> 4;
    const int tc   = t & 15;
    const int bn0  = tile * 128;

    const float* qbase = q + (size_t)bn0 * DM + m * DB;
    #pragma unroll
    for (int it = 0; it < 16; ++it) {
        int idx = it * 256 + t;
        int row = idx >> 5;
        int c4  = (idx & 31) << 2;
        *(float4*)&q_lds[row * 132 + c4] = *(const float4*)(qbase + (size_t)row * DM + c4);
    }

    float bestv[8]; int besti[8];
    #pragma unroll
    for (int i = 0; i < 8; ++i) { bestv[i] = 3.4e38f; besti[i] = 0; }
    const float* cbase = mem + (size_t)m * NPROTO * DB;

    for (int ch = 0; ch < 4; ++ch) {
        __syncthreads();
        const float* cb = cbase + (size_t)ch * 128 * DB;
        #pragma unroll
        for (int it = 0; it < 16; ++it) {
            int idx = it * 256 + t;
            int row = idx >> 5;
            int c4  = (idx & 31) << 2;
            *(float4*)&c_lds[row * 132 + c4] = *(const float4*)(cb + row * DB + c4);
        }
        __syncthreads();

        float acc[8][8];
        #pragma unroll
        for (int i = 0; i < 8; ++i)
            #pragma unroll
            for (int j = 0; j < 8; ++j) acc[i][j] = 0.f;

        for (int d4 = 0; d4 < DB; d4 += 4) {
            float4 qa[8], cvv[8];
            #pragma unroll
            for (int i = 0; i < 8; ++i) qa[i] = *(const float4*)&q_lds[(tr + 16 * i) * 132 + d4];
            #pragma unroll
            for (int j = 0; j < 8; ++j) cvv[j] = *(const float4*)&c_lds[(tc + 16 * j) * 132 + d4];
            #pragma unroll
            for (int i = 0; i < 8; ++i)
                #pragma unroll
                for (int j = 0; j < 8; ++j) {
                    acc[i][j] += qa[i].x * cvv[j].x; acc[i][j] += qa[i].y * cvv[j].y;
                    acc[i][j] += qa[i].z * cvv[j].z; acc[i][j] += qa[i].w * cvv[j].w;
                }
        }
        #pragma unroll
        for (int i = 0; i < 8; ++i)
            #pragma unroll
            for (int j = 0; j < 8; ++j) {
                int lp = ch * 128 + tc + 16 * j;
                float dist = cn[m * NPROTO + lp] - 2.0f * acc[i][j];
                if (dist < bestv[i]) { bestv[i] = dist; besti[i] = lp; }
            }
    }

    #pragma unroll
    for (int i = 0; i < 8; ++i) {
        float v = bestv[i]; int ix = besti[i];
        #pragma unroll
        for (int off = 1; off < 16; off <<= 1) {
            float v2 = __shfl_xor(v, off, 64);
            int  ix2 = __shfl_xor(ix, off, 64);
            if (v2 < v || (v2 == v && ix2 < ix)) { v = v2; ix = ix2; }
        }
        bestv[i] = v; besti[i] = ix;
    }

    float lacc = 0.f;
    #pragma unroll
    for (int i = 0; i < 8; ++i) {
        int row = tr + 16 * i;
        int bn  = bn0 + row;
        const float* cvec = cbase + (size_t)besti[i] * DB;
        float* orow = out + (size_t)bn * DM + m * DB;
        #pragma unroll
        for (int h = 0; h < 2; ++h) {
            int col = h * 64 + tc * 4;
            float4 c4v = *(const float4*)(cvec + col);
            *(float4*)(orow + col) = c4v;
            float4 qv2 = *(const float4*)&q_lds[row * 132 + col];
            float dx = c4v.x - qv2.x, dy = c4v.y - qv2.y;
            float dz = c4v.z - qv2.z, dw = c4v.w - qv2.w;
            lacc += dx * dx + dy * dy + dz * dz + dw * dw;
        }
        if (tc == 0)
            out[(size_t)IDX_OFF + (size_t)bn * NBLK + m] = (float)(m * NPROTO + besti[i]);
    }

    red[t] = lacc;
    __syncthreads();
    for (int s = 128; s > 0; s >>= 1) {
        if (t < s) red[t] += red[t + s];
        __syncthreads();
    }
    if (t == 0) partials[blockIdx.y * gridDim.x + blockIdx.x] = red[0];
}

__global__ __launch_bounds__(256) void vq_final(const float* __restrict__ partials,
                                                float* __restrict__ out, int n) {
    __shared__ float red[256];
    int t = threadIdx.x;
    float v = (t < n) ? partials[t] : 0.f;
    if (t + 256 < n) v += partials[t + 256];
    red[t] = v;
    __syncthreads();
    for (int s = 128; s > 0; s >>= 1) {
        if (t < s) red[t] += red[t + s];
        __syncthreads();
    }
    if (t == 0) {
        out[VQ_OFF] = 0.f;
        out[CL_OFF] = red[0] / 8388608.0f;
    }
}

extern "C" void kernel_launch(void* const* d_in, const int* in_sizes, int n_in,
                              void* d_out, int out_size, void* d_ws, size_t ws_size,
                              hipStream_t stream) {
    const float* q   = (const float*)d_in[0];
    const float* mem = (const float*)d_in[1];
    float* out = (float*)d_out;
    char* ws = (char*)d_ws;

    if (ws_size >= (size_t)WS_NEED) {
        u16*   bhp = (u16*)(ws + BH_B);
        u16*   blp = (u16*)(ws + BL_B);
        float* cnp = (float*)(ws + CN_B);
        float* partials = (float*)(ws + PART_B);

        vq_prep<<<128, 256, 0, stream>>>(mem, bhp, blp, cnp);
        dim3 grid(64, 8);
        vq_fused<<<grid, 256, 0, stream>>>(q, mem, bhp, blp, cnp, out, partials);
        vq_final<<<1, 256, 0, stream>>>(partials, out, 512);
    } else {
        float* cn = (float*)ws;
        float* partials = cn + 4096;
        vq_init<<<16, 256, 0, stream>>>(mem, cn);
        dim3 grid(64, 8);
        vq_main_f32<<<grid, 256, 0, stream>>>(q, mem, cn, out, partials);
        vq_final<<<1, 256, 0, stream>>>(partials, out, 512);
    }
}

// Round 9
// 72.760 us; speedup vs baseline: 1.0065x; 1.0065x over previous
//
#include <hip/hip_runtime.h>

#define NPROTO 512
#define NBLK 8
#define DB 128
#define DM 1024
#define TMR 128         // query rows per block (4 waves x 32 rows, ai=2)
#define PCH 32          // protos per chunk (16 chunks)

#define IDX_OFF  8388608
#define VQ_OFF   8454144
#define CL_OFF   8454145

typedef unsigned short u16;
typedef __attribute__((ext_vector_type(8))) _Float16 f16x8;
typedef __attribute__((ext_vector_type(4))) float f32x4;

// ---- ws layout (bytes) ----
#define BH_B   0u
#define BL_B   1048576u
#define CN_B   2097152u
#define PART_B 2113536u
#define WS_NEED (PART_B + 4096u)

__device__ __forceinline__ void gl_lds16(const u16* g, u16* l) {
    __builtin_amdgcn_global_load_lds(
        (const __attribute__((address_space(1))) unsigned int*)g,
        (__attribute__((address_space(3))) unsigned int*)l, 16, 0, 0);
}

// ---- prep: split codes into 2 f16 planes + per-proto sq-norms ----
__global__ __launch_bounds__(256) void vq_prep(const float* __restrict__ src,
                                               u16* __restrict__ hi,
                                               u16* __restrict__ lo,
                                               float* __restrict__ cn) {
    const int t  = threadIdx.x;
    const int p  = blockIdx.x * 32 + (t >> 3);
    const int e0 = (t & 7) * 16;
    const float* s = src + (size_t)p * DB + e0;
    float sq = 0.f;
    #pragma unroll
    for (int j = 0; j < 4; ++j) {
        float4 v = *(const float4*)(s + j * 4);
        ushort4 h, l;
        float x; _Float16 hf;
        #define S1(c, f) x = v.c; hf = (_Float16)x; h.f = __builtin_bit_cast(u16, hf); \
            hf = (_Float16)(x - (float)hf); l.f = __builtin_bit_cast(u16, hf); sq += x * x;
        S1(x, x) S1(y, y) S1(z, z) S1(w, w)
        #undef S1
        size_t o4 = ((size_t)p * DB + e0) / 4 + j;
        ((ushort4*)hi)[o4] = h;
        ((ushort4*)lo)[o4] = l;
    }
    sq += __shfl_xor(sq, 1, 64);
    sq += __shfl_xor(sq, 2, 64);
    sq += __shfl_xor(sq, 4, 64);
    if ((t & 7) == 0) cn[p] = sq;
}

// ================= fused MFMA main kernel =================
// r8 post-mortem: 128-VGPR cap is immovable; r8's live ~132 spilled.
// r9: keep ai=2 reuse (halved LDS reads) but PCH=32 (fj=2): acc 32->16,
// live ~116 < 128 -> no spill. B rows stored full-128d (16 slots) with
// slot XOR (proto&15) swizzle on both gl_lds source and ds_read.
// MFMA accumulation order identical to r8 (bit-identical dists -> no flips).
__global__ __launch_bounds__(256, 2) void vq_fused(
        const float* __restrict__ q, const float* __restrict__ mem,
        const u16* __restrict__ bh, const u16* __restrict__ bl,
        const float* __restrict__ cn, float* __restrict__ out,
        float* __restrict__ partials) {
    __shared__ u16 Bt[2][2][PCH][DB];  // [dbuf][plane][proto][d] = 32 KB
    __shared__ float qn_lds[TMR];
    __shared__ int   bp[TMR];
    __shared__ float red[16];

    const int t    = threadIdx.x;
    const int lane = t & 63;
    const int w    = t >> 6;          // 0..3
    const int lrow = lane & 15;
    const int lk   = lane >> 4;       // 0..3
    const int m    = blockIdx.y;
    const int bn0  = blockIdx.x * TMR;

    // ---- staging: 16KB chunk = 16 units of 1KB; wave w issues units 4w..4w+3
    // unit u: plane = u&1, proto-quad = u>>1; lane l -> proto quad*4+(l>>4),
    // slot (l&15), source slot pre-XORed by (proto&15) so linear LDS dest +
    // swizzled read compose to identity (both-sides rule).
#define STAGE(ch_, nb_) do { \
    _Pragma("unroll") \
    for (int c_ = 0; c_ < 4; ++c_) { \
        const int u_  = w * 4 + c_; \
        const int pl_ = u_ & 1; \
        const int qd_ = u_ >> 1; \
        const int pr_ = qd_ * 4 + (lane >> 4); \
        const u16* gs_ = (pl_ ? bl : bh) \
            + (size_t)(m * NPROTO + (ch_) * PCH + pr_) * DB \
            + (((lane & 15) ^ (pr_ & 15)) * 8); \
        gl_lds16(gs_, &Bt[(nb_)][pl_][qd_ * 4][0]); \
    } \
} while (0)

    STAGE(0, 0);   // prefetch first chunk; overlaps A load/convert below

    // ---- A: 2 q-rows per lane, f32 -> 2 f16 planes in registers ----
    f16x8 ah[2][4], al[2][4];
    #pragma unroll
    for (int ai = 0; ai < 2; ++ai) {
        float qnp = 0.f;
        #pragma unroll
        for (int kst = 0; kst < 4; ++kst) {
            const float* src = q + (size_t)(bn0 + w * 32 + ai * 16 + lrow) * DM
                                 + m * DB + kst * 32 + lk * 8;
            float4 v0 = *(const float4*)src;
            float4 v1 = *(const float4*)(src + 4);
            f16x8 hv, lv;
            float x; _Float16 hh;
            #define SA(e, val) x = (val); hh = (_Float16)x; hv[e] = hh; \
                lv[e] = (_Float16)(x - (float)hh); qnp += x * x;
            SA(0, v0.x) SA(1, v0.y) SA(2, v0.z) SA(3, v0.w)
            SA(4, v1.x) SA(5, v1.y) SA(6, v1.z) SA(7, v1.w)
            #undef SA
            ah[ai][kst] = hv; al[ai][kst] = lv;
        }
        qnp += __shfl_xor(qnp, 16, 64);
        qnp += __shfl_xor(qnp, 32, 64);
        if (lk == 0) qn_lds[w * 32 + ai * 16 + lrow] = qnp;
    }

    float bestv[2][4]; int besti[2][4];
    #pragma unroll
    for (int ai = 0; ai < 2; ++ai)
        #pragma unroll
        for (int r = 0; r < 4; ++r) { bestv[ai][r] = 3.4e38f; besti[ai][r] = 0; }

    const float* cnbase = cn + m * NPROTO + lrow;

    __syncthreads();   // chunk 0 staged + qn_lds visible

    #pragma unroll
    for (int ch = 0; ch < 16; ++ch) {
        const int buf = ch & 1;
        if (ch < 15) STAGE(ch + 1, buf ^ 1);

        // prefetch cn for this chunk's fold (hidden under MFMAs)
        const float cn0 = cnbase[ch * PCH];
        const float cn1 = cnbase[ch * PCH + 16];

        f32x4 acc[2][2];
        #pragma unroll
        for (int ai = 0; ai < 2; ++ai)
            #pragma unroll
            for (int fj = 0; fj < 2; ++fj) acc[ai][fj] = (f32x4){0.f, 0.f, 0.f, 0.f};

        #pragma unroll
        for (int kst = 0; kst < 4; ++kst) {
            #pragma unroll
            for (int fj = 0; fj < 2; ++fj) {
                const int rowb = fj * 16 + lrow;
                const int so   = (((kst * 4 + lk) ^ lrow) * 8);
                f16x8 Bh = *(const f16x8*)&Bt[buf][0][rowb][so];
                f16x8 Bl = *(const f16x8*)&Bt[buf][1][rowb][so];
                #pragma unroll
                for (int ai = 0; ai < 2; ++ai) {
                    f32x4 a = acc[ai][fj];
                    a = __builtin_amdgcn_mfma_f32_16x16x32_f16(ah[ai][kst], Bh, a, 0, 0, 0);
                    a = __builtin_amdgcn_mfma_f32_16x16x32_f16(al[ai][kst], Bh, a, 0, 0, 0);
                    a = __builtin_amdgcn_mfma_f32_16x16x32_f16(ah[ai][kst], Bl, a, 0, 0, 0);
                    acc[ai][fj] = a;
                }
            }
        }

        // fold chunk into running argmin; dist' = cn - 2*dot (qn-free,
        // argmin-invariant; qn added back at publish for the loss)
        #pragma unroll
        for (int fj = 0; fj < 2; ++fj) {
            const int   ploc = ch * PCH + fj * 16 + lrow;
            const float cnv  = fj ? cn1 : cn0;
            #pragma unroll
            for (int ai = 0; ai < 2; ++ai)
                #pragma unroll
                for (int r = 0; r < 4; ++r) {
                    float d = cnv - 2.0f * acc[ai][fj][r];
                    if (d < bestv[ai][r]) { bestv[ai][r] = d; besti[ai][r] = ploc; }
                }
        }
        __syncthreads();
    }

    // ---- butterfly argmin over the 16 proto-lanes ----
    #pragma unroll
    for (int ai = 0; ai < 2; ++ai)
        #pragma unroll
        for (int r = 0; r < 4; ++r) {
            float v = bestv[ai][r]; int ix = besti[ai][r];
            #pragma unroll
            for (int off = 1; off < 16; off <<= 1) {
                float v2 = __shfl_xor(v, off, 64);
                int  ix2 = __shfl_xor(ix, off, 64);
                if (v2 < v || (v2 == v && ix2 < ix)) { v = v2; ix = ix2; }
            }
            bestv[ai][r] = v; besti[ai][r] = ix;
        }

    // ---- lanes lrow==0 publish results for their 8 rows ----
    if (lrow == 0) {
        float lp = 0.f;
        #pragma unroll
        for (int ai = 0; ai < 2; ++ai)
            #pragma unroll
            for (int r = 0; r < 4; ++r) {
                int row = w * 32 + ai * 16 + lk * 4 + r;
                bp[row] = besti[ai][r];
                out[(size_t)IDX_OFF + (size_t)(bn0 + row) * NBLK + m] =
                    (float)(m * NPROTO + besti[ai][r]);
                lp += bestv[ai][r] + qn_lds[row];   // true distance for the loss
            }
        red[w * 4 + lk] = lp;
    }
    __syncthreads();

    // ---- gather winning code rows (exact f32 copy) ----
    {
        int row = t >> 1, hf = t & 1;
        int bpi = bp[row];
        const float* cv = mem + ((size_t)(m * NPROTO + bpi)) * DB + hf * 64;
        float* ov = out + (size_t)(bn0 + row) * DM + m * DB + hf * 64;
        #pragma unroll
        for (int j = 0; j < 16; ++j)
            *(float4*)(ov + j * 4) = *(const float4*)(cv + j * 4);
    }
    if (t == 0) {
        float s = 0.f;
        #pragma unroll
        for (int i = 0; i < 16; ++i) s += red[i];
        partials[blockIdx.y * gridDim.x + blockIdx.x] = s;
    }
#undef STAGE
}

// ================= fallback f32 path (used only if ws too small) =============
__global__ __launch_bounds__(256) void vq_init(const float* __restrict__ mem,
                                               float* __restrict__ cn) {
    int p = blockIdx.x * 256 + threadIdx.x;
    const float* c = mem + (size_t)p * DB;
    float s = 0.f;
    #pragma unroll 8
    for (int k = 0; k < DB; k += 4) {
        float4 v = *(const float4*)(c + k);
        s += v.x * v.x + v.y * v.y + v.z * v.z + v.w * v.w;
    }
    cn[p] = s;
}

__global__ __launch_bounds__(256, 1) void vq_main_f32(const float* __restrict__ q,
                                                      const float* __restrict__ mem,
                                                      const float* __restrict__ cn,
                                                      float* __restrict__ out,
                                                      float* __restrict__ partials) {
    __shared__ float q_lds[128 * 132];
    __shared__ float c_lds[128 * 132];
    __shared__ float red[256];

    const int t    = threadIdx.x;
    const int tile = blockIdx.x;
    const int m    = blockIdx.y;
    const int tr   = t >> 4;
    const int tc   = t & 15;
    const int bn0  = tile * 128;

    const float* qbase = q + (size_t)bn0 * DM + m * DB;
    #pragma unroll
    for (int it = 0; it < 16; ++it) {
        int idx = it * 256 + t;
        int row = idx >> 5;
        int c4  = (idx & 31) << 2;
        *(float4*)&q_lds[row * 132 + c4] = *(const float4*)(qbase + (size_t)row * DM + c4);
    }

    float bestv[8]; int besti[8];
    #pragma unroll
    for (int i = 0; i < 8; ++i) { bestv[i] = 3.4e38f; besti[i] = 0; }
    const float* cbase = mem + (size_t)m * NPROTO * DB;

    for (int ch = 0; ch < 4; ++ch) {
        __syncthreads();
        const float* cb = cbase + (size_t)ch * 128 * DB;
        #pragma unroll
        for (int it = 0; it < 16; ++it) {
            int idx = it * 256 + t;
            int row = idx >> 5;
            int c4  = (idx & 31) << 2;
            *(float4*)&c_lds[row * 132 + c4] = *(const float4*)(cb + row * DB + c4);
        }
        __syncthreads();

        float acc[8][8];
        #pragma unroll
        for (int i = 0; i < 8; ++i)
            #pragma unroll
            for (int j = 0; j < 8; ++j) acc[i][j] = 0.f;

        for (int d4 = 0; d4 < DB; d4 += 4) {
            float4 qa[8], cvv[8];
            #pragma unroll
            for (int i = 0; i < 8; ++i) qa[i] = *(const float4*)&q_lds[(tr + 16 * i) * 132 + d4];
            #pragma unroll
            for (int j = 0; j < 8; ++j) cvv[j] = *(const float4*)&c_lds[(tc + 16 * j) * 132 + d4];
            #pragma unroll
            for (int i = 0; i < 8; ++i)
                #pragma unroll
                for (int j = 0; j < 8; ++j) {
                    acc[i][j] += qa[i].x * cvv[j].x; acc[i][j] += qa[i].y * cvv[j].y;
                    acc[i][j] += qa[i].z * cvv[j].z; acc[i][j] += qa[i].w * cvv[j].w;
                }
        }
        #pragma unroll
        for (int i = 0; i < 8; ++i)
            #pragma unroll
            for (int j = 0; j < 8; ++j) {
                int lp = ch * 128 + tc + 16 * j;
                float dist = cn[m * NPROTO + lp] - 2.0f * acc[i][j];
                if (dist < bestv[i]) { bestv[i] = dist; besti[i] = lp; }
            }
    }

    #pragma unroll
    for (int i = 0; i < 8; ++i) {
        float v = bestv[i]; int ix = besti[i];
        #pragma unroll
        for (int off = 1; off < 16; off <<= 1) {
            float v2 = __shfl_xor(v, off, 64);
            int  ix2 = __shfl_xor(ix, off, 64);
            if (v2 < v || (v2 == v && ix2 < ix)) { v = v2; ix = ix2; }
        }
        bestv[i] = v; besti[i] = ix;
    }

    float lacc = 0.f;
    #pragma unroll
    for (int i = 0; i < 8; ++i) {
        int row = tr + 16 * i;
        int bn  = bn0 + row;
        const float* cvec = cbase + (size_t)besti[i] * DB;
        float* orow = out + (size_t)bn * DM + m * DB;
        #pragma unroll
        for (int h = 0; h < 2; ++h) {
            int col = h * 64 + tc * 4;
            float4 c4v = *(const float4*)(cvec + col);
            *(float4*)(orow + col) = c4v;
            float4 qv2 = *(const float4*)&q_lds[row * 132 + col];
            float dx = c4v.x - qv2.x, dy = c4v.y - qv2.y;
            float dz = c4v.z - qv2.z, dw = c4v.w - qv2.w;
            lacc += dx * dx + dy * dy + dz * dz + dw * dw;
        }
        if (tc == 0)
            out[(size_t)IDX_OFF + (size_t)bn * NBLK + m] = (float)(m * NPROTO + besti[i]);
    }

    red[t] = lacc;
    __syncthreads();
    for (int s = 128; s > 0; s >>= 1) {
        if (t < s) red[t] += red[t + s];
        __syncthreads();
    }
    if (t == 0) partials[blockIdx.y * gridDim.x + blockIdx.x] = red[0];
}

__global__ __launch_bounds__(256) void vq_final(const float* __restrict__ partials,
                                                float* __restrict__ out, int n) {
    __shared__ float red[256];
    int t = threadIdx.x;
    float v = (t < n) ? partials[t] : 0.f;
    if (t + 256 < n) v += partials[t + 256];
    red[t] = v;
    __syncthreads();
    for (int s = 128; s > 0; s >>= 1) {
        if (t < s) red[t] += red[t + s];
        __syncthreads();
    }
    if (t == 0) {
        out[VQ_OFF] = 0.f;
        out[CL_OFF] = red[0] / 8388608.0f;
    }
}

extern "C" void kernel_launch(void* const* d_in, const int* in_sizes, int n_in,
                              void* d_out, int out_size, void* d_ws, size_t ws_size,
                              hipStream_t stream) {
    const float* q   = (const float*)d_in[0];
    const float* mem = (const float*)d_in[1];
    float* out = (float*)d_out;
    char* ws = (char*)d_ws;

    if (ws_size >= (size_t)WS_NEED) {
        u16*   bhp = (u16*)(ws + BH_B);
        u16*   blp = (u16*)(ws + BL_B);
        float* cnp = (float*)(ws + CN_B);
        float* partials = (float*)(ws + PART_B);

        vq_prep<<<128, 256, 0, stream>>>(mem, bhp, blp, cnp);
        dim3 grid(64, 8);
        vq_fused<<<grid, 256, 0, stream>>>(q, mem, bhp, blp, cnp, out, partials);
        vq_final<<<1, 256, 0, stream>>>(partials, out, 512);
    } else {
        float* cn = (float*)ws;
        float* partials = cn + 4096;
        vq_init<<<16, 256, 0, stream>>>(mem, cn);
        dim3 grid(64, 8);
        vq_main_f32<<<grid, 256, 0, stream>>>(q, mem, cn, out, partials);
        vq_final<<<1, 256, 0, stream>>>(partials, out, 512);
    }
}